// Round 3
// baseline (432.236 us; speedup 1.0000x reference)
//
#include <hip/hip_runtime.h>
#include <hip/hip_bf16.h>

#define EPS_BN 1e-5f

// Problem constants: B=8, CH=64, H=W=64  (all I/O is float32 per the reference)
constexpr int Bn   = 8;
constexpr int CHn  = 64;
constexpr int HWn  = 4096;   // 64*64
constexpr int HW4n = 1024;   // pooled
constexpr int CQn  = 8;      // CH/8
constexpr int CVn  = 32;     // CH/2

// Module-scope scratch (no d_ws size assumption). Fully rewritten every call.
__device__ __align__(16) float g_K[Bn * HW4n * CQn];   // [b][m][8]   256 KiB
__device__ __align__(16) float g_V[Bn * HW4n * CVn];   // [b][m][32]  1 MiB

// ------------- Kernel A: K,V projection + BN + 2x2 maxpool -------------------
// 32 blocks x 256 threads; thread = one pooled pixel (b, m).
__global__ __launch_bounds__(256)
void k_proj_kv(const float* __restrict__ mem,
               const float* __restrict__ wk,  const float* __restrict__ bk,
               const float* __restrict__ ks,  const float* __restrict__ kb,
               const float* __restrict__ km,  const float* __restrict__ kv,
               const float* __restrict__ wv,  const float* __restrict__ bv_,
               const float* __restrict__ vs,  const float* __restrict__ vb,
               const float* __restrict__ vm,  const float* __restrict__ vv)
{
    __shared__ float wall[2560];   // [ch][40]: c 0..7 = k channels, 8..39 = v (inv folded)
    __shared__ float beta[40];
    const int tid = threadIdx.x;
    for (int idx = tid; idx < 2560; idx += 256) {
        int c = idx % 40, ch = idx / 40;
        float w, inv;
        if (c < 8) { inv = ks[c] * rsqrtf(kv[c] + EPS_BN); w = wk[c * 64 + ch]; }
        else { int c2 = c - 8; inv = vs[c2] * rsqrtf(vv[c2] + EPS_BN); w = wv[c2 * 64 + ch]; }
        wall[ch * 40 + c] = w * inv;
    }
    if (tid < 40) {
        int c = tid;
        if (c < 8) {
            float inv = ks[c] * rsqrtf(kv[c] + EPS_BN);
            beta[c] = (bk[c] - km[c]) * inv + kb[c];
        } else {
            int c2 = c - 8;
            float inv = vs[c2] * rsqrtf(vv[c2] + EPS_BN);
            beta[c] = (bv_[c2] - vm[c2]) * inv + vb[c2];
        }
    }
    __syncthreads();

    const int b = blockIdx.x >> 2;                 // 4 blocks per batch
    const int m = ((blockIdx.x & 3) << 8) | tid;   // pooled pixel
    const int h2 = m >> 5, w2 = m & 31;
    const float* mb = mem + (size_t)b * CHn * HWn;

    float kmax[8], vmax[32];
    #pragma unroll
    for (int c = 0; c < 8; ++c) kmax[c] = -3.0e38f;
    #pragma unroll
    for (int c = 0; c < 32; ++c) vmax[c] = -3.0e38f;

    for (int pix = 0; pix < 4; ++pix) {
        const int n = (2 * h2 + (pix >> 1)) * 64 + 2 * w2 + (pix & 1);
        float acc[40];
        #pragma unroll
        for (int c = 0; c < 40; ++c) acc[c] = 0.f;
        for (int ch = 0; ch < 64; ++ch) {
            float mv = mb[ch * HWn + n];
            const float4* wr = (const float4*)&wall[ch * 40];
            #pragma unroll
            for (int k4 = 0; k4 < 10; ++k4) {
                float4 w = wr[k4];
                acc[4*k4+0] = fmaf(w.x, mv, acc[4*k4+0]);
                acc[4*k4+1] = fmaf(w.y, mv, acc[4*k4+1]);
                acc[4*k4+2] = fmaf(w.z, mv, acc[4*k4+2]);
                acc[4*k4+3] = fmaf(w.w, mv, acc[4*k4+3]);
            }
        }
        #pragma unroll
        for (int c = 0; c < 8; ++c)  kmax[c] = fmaxf(kmax[c], acc[c] + beta[c]);
        #pragma unroll
        for (int c = 0; c < 32; ++c) vmax[c] = fmaxf(vmax[c], acc[8 + c] + beta[8 + c]);
    }

    float4* kp = (float4*)(g_K + ((size_t)b * HW4n + m) * CQn);
    kp[0] = make_float4(kmax[0], kmax[1], kmax[2], kmax[3]);
    kp[1] = make_float4(kmax[4], kmax[5], kmax[6], kmax[7]);
    float4* vp = (float4*)(g_V + ((size_t)b * HW4n + m) * CVn);
    #pragma unroll
    for (int j = 0; j < 8; ++j)
        vp[j] = make_float4(vmax[4*j], vmax[4*j+1], vmax[4*j+2], vmax[4*j+3]);
}

// ------ Kernel B: fused Q-proj + attention + out-proj + residual -------------
// 256 blocks x 128 threads. Thread = one query n; iterates all 1024 keys.
__global__ __launch_bounds__(128)
void k_attn2(const float* __restrict__ mem,
             const float* __restrict__ x,
             const float* __restrict__ wq, const float* __restrict__ bq,
             const float* __restrict__ qs, const float* __restrict__ qb,
             const float* __restrict__ qm, const float* __restrict__ qv,
             const float* __restrict__ wp, const float* __restrict__ bp,
             const float* __restrict__ ps, const float* __restrict__ pb,
             const float* __restrict__ pm, const float* __restrict__ pv,
             const float* __restrict__ gamma,
             float* __restrict__ out)
{
    __shared__ float qw[512];      // folded Q weights [ch][c]
    __shared__ float qbeta[8];
    __shared__ float Ksh[8192];    // K[1024][8] fp32, 32 KB
    __shared__ float Vsh[4096];    // V chunk: 128 rows x 32, 16 KB
    __shared__ float wpf[2048];    // folded out-proj weights [o][c], 8 KB
    __shared__ float pbeta[64];

    const int tid  = threadIdx.x;        // 0..127
    const int b    = blockIdx.x >> 5;    // 32 tiles per batch
    const int tile = blockIdx.x & 31;
    const int n    = (tile << 7) | tid;  // query pixel

    // ---- stage folded weights ----
    const float gm = gamma[0];
    for (int idx = tid; idx < 512; idx += 128) {
        int c = idx & 7, ch = idx >> 3;
        float inv = qs[c] * rsqrtf(qv[c] + EPS_BN);
        qw[ch * 8 + c] = wq[c * 64 + ch] * inv;
    }
    if (tid < 8) {
        float inv = qs[tid] * rsqrtf(qv[tid] + EPS_BN);
        qbeta[tid] = (bq[tid] - qm[tid]) * inv + qb[tid];
    }
    for (int idx = tid; idx < 2048; idx += 128) {
        int o = idx >> 5, cc = idx & 31;
        float inv = ps[o] * rsqrtf(pv[o] + EPS_BN);
        wpf[idx] = wp[o * 32 + cc] * inv * gm;
    }
    if (tid < 64) {
        float inv = ps[tid] * rsqrtf(pv[tid] + EPS_BN);
        pbeta[tid] = gm * ((bp[tid] - pm[tid]) * inv + pb[tid]);
    }
    // ---- stage K (this batch) ----
    {
        const float4* Ksrc = (const float4*)(g_K + (size_t)b * HW4n * CQn);
        float4* Kdst = (float4*)Ksh;
        #pragma unroll
        for (int i = 0; i < 16; ++i) Kdst[i * 128 + tid] = Ksrc[i * 128 + tid];
    }
    __syncthreads();

    // ---- compute this thread's query (conv1x1 + BN folded) ----
    float a0=0,a1=0,a2=0,a3=0,a4=0,a5=0,a6=0,a7=0;
    {
        const float* mp = mem + (size_t)b * CHn * HWn + n;
        for (int ch = 0; ch < 64; ++ch) {
            float mv = mp[ch * HWn];
            const float4* wr = (const float4*)&qw[ch * 8];
            float4 w0 = wr[0], w1 = wr[1];
            a0 = fmaf(w0.x, mv, a0); a1 = fmaf(w0.y, mv, a1);
            a2 = fmaf(w0.z, mv, a2); a3 = fmaf(w0.w, mv, a3);
            a4 = fmaf(w1.x, mv, a4); a5 = fmaf(w1.y, mv, a5);
            a6 = fmaf(w1.z, mv, a6); a7 = fmaf(w1.w, mv, a7);
        }
    }
    const float4 q0 = make_float4(a0 + qbeta[0], a1 + qbeta[1], a2 + qbeta[2], a3 + qbeta[3]);
    const float4 q1 = make_float4(a4 + qbeta[4], a5 + qbeta[5], a6 + qbeta[6], a7 + qbeta[7]);

    const float4* K4 = (const float4*)Ksh;
    auto score = [&](int m) -> float {
        const float4 k0 = K4[2 * m], k1 = K4[2 * m + 1];
        return fmaf(q0.x, k0.x, fmaf(q0.y, k0.y, fmaf(q0.z, k0.z, fmaf(q0.w, k0.w,
               fmaf(q1.x, k1.x, fmaf(q1.y, k1.y, fmaf(q1.z, k1.z, q1.w * k1.w)))))));
    };

    // ---- pass 1: softmax max over all 1024 keys ----
    float mx = -3.0e38f;
    for (int m = 0; m < 1024; ++m) mx = fmaxf(mx, score(m));

    // ---- pass 2: exp + PV accumulate; V streamed in 128-row chunks ----
    float l = 0.f;
    float acc[32];
    #pragma unroll
    for (int j = 0; j < 32; ++j) acc[j] = 0.f;

    for (int c = 0; c < 8; ++c) {
        __syncthreads();   // previous chunk fully consumed
        {
            const float4* Vs = (const float4*)(g_V + (size_t)b * HW4n * CVn + c * 4096);
            float4* Vd = (float4*)Vsh;
            #pragma unroll
            for (int i = 0; i < 8; ++i) Vd[i * 128 + tid] = Vs[i * 128 + tid];
        }
        __syncthreads();
        const float4* V4 = (const float4*)Vsh;
        for (int mm = 0; mm < 128; ++mm) {
            const int m = (c << 7) | mm;
            float p = __expf(score(m) - mx);
            l += p;
            const float4* vr = V4 + mm * 8;
            #pragma unroll
            for (int j4 = 0; j4 < 8; ++j4) {
                float4 vv = vr[j4];
                acc[4*j4+0] = fmaf(p, vv.x, acc[4*j4+0]);
                acc[4*j4+1] = fmaf(p, vv.y, acc[4*j4+1]);
                acc[4*j4+2] = fmaf(p, vv.z, acc[4*j4+2]);
                acc[4*j4+3] = fmaf(p, vv.w, acc[4*j4+3]);
            }
        }
    }

    // ---- normalize, out-projection, residual ----
    const float rL = 1.0f / l;
    float g[32];
    #pragma unroll
    for (int j = 0; j < 32; ++j) g[j] = acc[j] * rL;

    const float* xp = x + (size_t)b * CHn * HWn + n;
    float* op = out + (size_t)b * CHn * HWn + n;
    const float4* wpf4 = (const float4*)wpf;
    for (int o = 0; o < 64; ++o) {
        float s = pbeta[o];
        #pragma unroll
        for (int c4 = 0; c4 < 8; ++c4) {
            float4 w = wpf4[o * 8 + c4];
            s += w.x * g[4*c4] + w.y * g[4*c4+1] + w.z * g[4*c4+2] + w.w * g[4*c4+3];
        }
        op[o * HWn] = xp[o * HWn] + s;
    }
}

// ------------------------------- launcher ------------------------------------
extern "C" void kernel_launch(void* const* d_in, const int* in_sizes, int n_in,
                              void* d_out, int out_size, void* d_ws, size_t ws_size,
                              hipStream_t stream)
{
    const float* x    = (const float*)d_in[0];
    const float* mem  = (const float*)d_in[1];
    const float* wq   = (const float*)d_in[2];
    const float* bq   = (const float*)d_in[3];
    const float* bnqs = (const float*)d_in[4];
    const float* bnqb = (const float*)d_in[5];
    const float* bnqm = (const float*)d_in[6];
    const float* bnqv = (const float*)d_in[7];
    const float* wk   = (const float*)d_in[8];
    const float* bk   = (const float*)d_in[9];
    const float* bnks = (const float*)d_in[10];
    const float* bnkb = (const float*)d_in[11];
    const float* bnkm = (const float*)d_in[12];
    const float* bnkv = (const float*)d_in[13];
    const float* wv   = (const float*)d_in[14];
    const float* bv   = (const float*)d_in[15];
    const float* bnvs = (const float*)d_in[16];
    const float* bnvb = (const float*)d_in[17];
    const float* bnvm = (const float*)d_in[18];
    const float* bnvv = (const float*)d_in[19];
    const float* wp   = (const float*)d_in[20];
    const float* bp   = (const float*)d_in[21];
    const float* bnps = (const float*)d_in[22];
    const float* bnpb = (const float*)d_in[23];
    const float* bnpm = (const float*)d_in[24];
    const float* bnpv = (const float*)d_in[25];
    const float* gam  = (const float*)d_in[26];

    (void)d_ws; (void)ws_size; (void)in_sizes; (void)n_in; (void)out_size;

    k_proj_kv<<<dim3(32), dim3(256), 0, stream>>>(mem,
        wk, bk, bnks, bnkb, bnkm, bnkv,
        wv, bv, bnvs, bnvb, bnvm, bnvv);
    k_attn2<<<dim3(256), dim3(128), 0, stream>>>(mem, x,
        wq, bq, bnqs, bnqb, bnqm, bnqv,
        wp, bp, bnps, bnpb, bnpm, bnpv, gam,
        (float*)d_out);
}

// Round 4
// 199.411 us; speedup vs baseline: 2.1676x; 2.1676x over previous
//
#include <hip/hip_runtime.h>

#define EPS_BN 1e-5f

// Problem constants: B=8, CH=64, H=W=64  (all I/O float32)
constexpr int Bn   = 8;
constexpr int CHn  = 64;
constexpr int HWn  = 4096;   // 64*64
constexpr int HW4n = 1024;   // pooled
constexpr int CQn  = 8;      // CH/8
constexpr int CVn  = 32;     // CH/2

// Module-scope scratch; fully rewritten every call.
__device__ __align__(16) float g_K[Bn * HW4n * CQn];   // [b][m][8]   256 KiB
__device__ __align__(16) float g_V[Bn * HW4n * CVn];   // [b][m][32]  1 MiB

// ------------- Kernel A: K,V projection + BN + 2x2 maxpool -------------------
// 128 blocks x 256 threads. 4-lane group = one pooled pixel; lane j owns one
// source pixel of the 2x2 quad; pool via shfl_xor(1)/(2). Coalesced loads.
__global__ __launch_bounds__(256)
void k_proj_kv(const float* __restrict__ mem,
               const float* __restrict__ wk,  const float* __restrict__ bk,
               const float* __restrict__ ks,  const float* __restrict__ kb,
               const float* __restrict__ km,  const float* __restrict__ kv,
               const float* __restrict__ wv,  const float* __restrict__ bv_,
               const float* __restrict__ vs,  const float* __restrict__ vb,
               const float* __restrict__ vm,  const float* __restrict__ vv)
{
    __shared__ float wall[2560];   // [ch][40]: c 0..7 = K, 8..39 = V (BN folded)
    __shared__ float beta[40];
    const int tid = threadIdx.x;
    for (int idx = tid; idx < 2560; idx += 256) {
        int c = idx % 40, ch = idx / 40;
        float w, inv;
        if (c < 8) { inv = ks[c] * rsqrtf(kv[c] + EPS_BN); w = wk[c * 64 + ch]; }
        else { int c2 = c - 8; inv = vs[c2] * rsqrtf(vv[c2] + EPS_BN); w = wv[c2 * 64 + ch]; }
        wall[ch * 40 + c] = w * inv;
    }
    if (tid < 40) {
        int c = tid;
        if (c < 8) {
            float inv = ks[c] * rsqrtf(kv[c] + EPS_BN);
            beta[c] = (bk[c] - km[c]) * inv + kb[c];
        } else {
            int c2 = c - 8;
            float inv = vs[c2] * rsqrtf(vv[c2] + EPS_BN);
            beta[c] = (bv_[c2] - vm[c2]) * inv + vb[c2];
        }
    }
    __syncthreads();

    const int b     = blockIdx.x >> 4;            // 16 blocks per batch
    const int mbase = (blockIdx.x & 15) << 6;     // 64 pooled px per block
    const int grp   = tid >> 2;
    const int j     = tid & 3;
    const int m     = mbase + grp;
    const int h2 = m >> 5, w2 = m & 31;
    const int n  = ((h2 << 1) + (j >> 1)) * 64 + (w2 << 1) + (j & 1);
    const float* mb = mem + (size_t)b * (CHn * HWn) + n;

    float acc[40];
    #pragma unroll
    for (int c = 0; c < 40; ++c) acc[c] = 0.f;
    for (int ch = 0; ch < 64; ++ch) {
        float mv = mb[ch * HWn];
        const float4* wr = (const float4*)&wall[ch * 40];
        #pragma unroll
        for (int k4 = 0; k4 < 10; ++k4) {
            float4 w = wr[k4];
            acc[4*k4+0] = fmaf(w.x, mv, acc[4*k4+0]);
            acc[4*k4+1] = fmaf(w.y, mv, acc[4*k4+1]);
            acc[4*k4+2] = fmaf(w.z, mv, acc[4*k4+2]);
            acc[4*k4+3] = fmaf(w.w, mv, acc[4*k4+3]);
        }
    }
    // 2x2 maxpool across the 4-lane group
    #pragma unroll
    for (int c = 0; c < 40; ++c) {
        acc[c] = fmaxf(acc[c], __shfl_xor(acc[c], 1));
        acc[c] = fmaxf(acc[c], __shfl_xor(acc[c], 2));
    }
    // distributed writes: lane j writes K ch {2j,2j+1}, V ch [8j, 8j+8)
    float* kp = g_K + ((size_t)b * HW4n + m) * CQn;
    ((float2*)kp)[j] = make_float2(acc[2*j] + beta[2*j], acc[2*j+1] + beta[2*j+1]);
    float4* vp = (float4*)(g_V + ((size_t)b * HW4n + m) * CVn + 8 * j);
    vp[0] = make_float4(acc[8+8*j+0] + beta[8+8*j+0], acc[8+8*j+1] + beta[8+8*j+1],
                        acc[8+8*j+2] + beta[8+8*j+2], acc[8+8*j+3] + beta[8+8*j+3]);
    vp[1] = make_float4(acc[8+8*j+4] + beta[8+8*j+4], acc[8+8*j+5] + beta[8+8*j+5],
                        acc[8+8*j+6] + beta[8+8*j+6], acc[8+8*j+7] + beta[8+8*j+7]);
}

// ------ Kernel B: fused Q-proj + attention + out-proj + residual -------------
// 512 blocks x 256 threads (2 blocks/CU, 8 waves/CU). 8-lane group owns 2
// queries; lane j handles keys ≡ j (mod 8); shfl_xor merge (shared max).
__global__ __launch_bounds__(256, 2)
void k_attn2(const float* __restrict__ mem,
             const float* __restrict__ x,
             const float* __restrict__ wq, const float* __restrict__ bq,
             const float* __restrict__ qs, const float* __restrict__ qb,
             const float* __restrict__ qm, const float* __restrict__ qv,
             const float* __restrict__ wp, const float* __restrict__ bp,
             const float* __restrict__ ps, const float* __restrict__ pb,
             const float* __restrict__ pm, const float* __restrict__ pv,
             const float* __restrict__ gamma,
             float* __restrict__ out)
{
    __shared__ float qw[512];      // folded Q weights [ch][8]
    __shared__ float qbeta[8];
    __shared__ float wpf[2048];    // folded out-proj weights [o][32]
    __shared__ float pbeta[64];
    __shared__ float Ksh[8192];    // K[1024][8], 32 KB
    __shared__ float Vsh[4608];    // V chunk: 128 rows x 36 (pad), 18 KB

    const int tid  = threadIdx.x;
    const int j    = tid & 7;            // key-split lane within group
    const int grp  = tid >> 3;           // 0..31, 2 queries each
    const int b    = blockIdx.x >> 6;    // 64 tiles per batch
    const int tile = blockIdx.x & 63;
    const int n0   = (tile << 6) + (grp << 1);   // group's first query
    const int nq   = n0 + (j & 1);               // epilogue query of this lane

    // ---- stage folded weights ----
    const float gm = gamma[0];
    for (int idx = tid; idx < 512; idx += 256) {
        int c = idx & 7, ch = idx >> 3;
        float inv = qs[c] * rsqrtf(qv[c] + EPS_BN);
        qw[idx] = wq[c * 64 + ch] * inv;
    }
    if (tid < 8) {
        float inv = qs[tid] * rsqrtf(qv[tid] + EPS_BN);
        qbeta[tid] = (bq[tid] - qm[tid]) * inv + qb[tid];
    }
    for (int idx = tid; idx < 2048; idx += 256) {
        int o = idx >> 5, cc = idx & 31;
        float inv = ps[o] * rsqrtf(pv[o] + EPS_BN);
        wpf[idx] = wp[o * 32 + cc] * inv * gm;
    }
    if (tid < 64) {
        float inv = ps[tid] * rsqrtf(pv[tid] + EPS_BN);
        pbeta[tid] = gm * ((bp[tid] - pm[tid]) * inv + pb[tid]);
    }
    // ---- stage K (this batch) ----
    {
        const float4* Ks4 = (const float4*)(g_K + (size_t)b * (HW4n * CQn));
        float4* Kd4 = (float4*)Ksh;
        #pragma unroll
        for (int i = 0; i < 8; ++i) Kd4[i * 256 + tid] = Ks4[i * 256 + tid];
    }
    __syncthreads();

    // ---- Q projection: lane j handles ch ≡ j (mod 8) for both queries ----
    float q0[8], q1[8];
    #pragma unroll
    for (int c = 0; c < 8; ++c) { q0[c] = 0.f; q1[c] = 0.f; }
    {
        const float* mp = mem + (size_t)b * (CHn * HWn) + n0;
        for (int cc = 0; cc < 8; ++cc) {
            int ch = (cc << 3) | j;
            float m0 = mp[ch * HWn];
            float m1 = mp[ch * HWn + 1];
            const float4* wr = (const float4*)&qw[ch * 8];
            float4 w0 = wr[0], w1 = wr[1];
            q0[0] = fmaf(w0.x, m0, q0[0]); q0[1] = fmaf(w0.y, m0, q0[1]);
            q0[2] = fmaf(w0.z, m0, q0[2]); q0[3] = fmaf(w0.w, m0, q0[3]);
            q0[4] = fmaf(w1.x, m0, q0[4]); q0[5] = fmaf(w1.y, m0, q0[5]);
            q0[6] = fmaf(w1.z, m0, q0[6]); q0[7] = fmaf(w1.w, m0, q0[7]);
            q1[0] = fmaf(w0.x, m1, q1[0]); q1[1] = fmaf(w0.y, m1, q1[1]);
            q1[2] = fmaf(w0.z, m1, q1[2]); q1[3] = fmaf(w0.w, m1, q1[3]);
            q1[4] = fmaf(w1.x, m1, q1[4]); q1[5] = fmaf(w1.y, m1, q1[5]);
            q1[6] = fmaf(w1.z, m1, q1[6]); q1[7] = fmaf(w1.w, m1, q1[7]);
        }
        #pragma unroll
        for (int c = 0; c < 8; ++c) {
            q0[c] += __shfl_xor(q0[c], 1); q0[c] += __shfl_xor(q0[c], 2); q0[c] += __shfl_xor(q0[c], 4);
            q1[c] += __shfl_xor(q1[c], 1); q1[c] += __shfl_xor(q1[c], 2); q1[c] += __shfl_xor(q1[c], 4);
            q0[c] += qbeta[c];
            q1[c] += qbeta[c];
        }
    }

    const float4* K4 = (const float4*)Ksh;
    auto dot8 = [](const float q[8], float4 k0, float4 k1) -> float {
        return fmaf(q[0], k0.x, fmaf(q[1], k0.y, fmaf(q[2], k0.z, fmaf(q[3], k0.w,
               fmaf(q[4], k1.x, fmaf(q[5], k1.y, fmaf(q[6], k1.z, q[7] * k1.w)))))));
    };

    // ---- pass 1: per-lane max over keys ≡ j (mod 8), then group max ----
    float mx0 = -3.0e38f, mx1 = -3.0e38f;
    for (int mm = 0; mm < 128; ++mm) {
        int m = (mm << 3) | j;
        float4 k0 = K4[2*m], k1 = K4[2*m+1];
        mx0 = fmaxf(mx0, dot8(q0, k0, k1));
        mx1 = fmaxf(mx1, dot8(q1, k0, k1));
    }
    mx0 = fmaxf(mx0, __shfl_xor(mx0, 1)); mx0 = fmaxf(mx0, __shfl_xor(mx0, 2)); mx0 = fmaxf(mx0, __shfl_xor(mx0, 4));
    mx1 = fmaxf(mx1, __shfl_xor(mx1, 1)); mx1 = fmaxf(mx1, __shfl_xor(mx1, 2)); mx1 = fmaxf(mx1, __shfl_xor(mx1, 4));

    // ---- pass 2: exp + PV accumulate; V streamed in 128-row padded chunks ----
    float l0 = 0.f, l1 = 0.f;
    float acc0[32], acc1[32];
    #pragma unroll
    for (int c = 0; c < 32; ++c) { acc0[c] = 0.f; acc1[c] = 0.f; }

    for (int c = 0; c < 8; ++c) {
        __syncthreads();   // previous chunk fully consumed
        {
            const float4* Vs4 = (const float4*)(g_V + (size_t)b * (HW4n * CVn)) + (c << 10);
            float4* Vd4 = (float4*)Vsh;
            #pragma unroll
            for (int i = 0; i < 4; ++i) {
                int idx = (i << 8) | tid;
                Vd4[(idx >> 3) * 9 + (idx & 7)] = Vs4[idx];
            }
        }
        __syncthreads();
        for (int mm = 0; mm < 16; ++mm) {
            const int rl = (mm << 3) | j;        // local row in chunk
            const int m  = (c << 7) | rl;        // global key
            float4 k0 = K4[2*m], k1 = K4[2*m+1];
            float e0 = __expf(dot8(q0, k0, k1) - mx0);
            float e1 = __expf(dot8(q1, k0, k1) - mx1);
            l0 += e0; l1 += e1;
            const float4* vr = (const float4*)&Vsh[rl * 36];
            #pragma unroll
            for (int q4 = 0; q4 < 8; ++q4) {
                float4 vv = vr[q4];
                acc0[4*q4+0] = fmaf(e0, vv.x, acc0[4*q4+0]);
                acc0[4*q4+1] = fmaf(e0, vv.y, acc0[4*q4+1]);
                acc0[4*q4+2] = fmaf(e0, vv.z, acc0[4*q4+2]);
                acc0[4*q4+3] = fmaf(e0, vv.w, acc0[4*q4+3]);
                acc1[4*q4+0] = fmaf(e1, vv.x, acc1[4*q4+0]);
                acc1[4*q4+1] = fmaf(e1, vv.y, acc1[4*q4+1]);
                acc1[4*q4+2] = fmaf(e1, vv.z, acc1[4*q4+2]);
                acc1[4*q4+3] = fmaf(e1, vv.w, acc1[4*q4+3]);
            }
        }
    }

    // ---- group-merge partial sums (shared max ⇒ direct sums) ----
    l0 += __shfl_xor(l0, 1); l0 += __shfl_xor(l0, 2); l0 += __shfl_xor(l0, 4);
    l1 += __shfl_xor(l1, 1); l1 += __shfl_xor(l1, 2); l1 += __shfl_xor(l1, 4);
    #pragma unroll
    for (int c = 0; c < 32; ++c) {
        acc0[c] += __shfl_xor(acc0[c], 1); acc0[c] += __shfl_xor(acc0[c], 2); acc0[c] += __shfl_xor(acc0[c], 4);
        acc1[c] += __shfl_xor(acc1[c], 1); acc1[c] += __shfl_xor(acc1[c], 2); acc1[c] += __shfl_xor(acc1[c], 4);
    }

    // ---- epilogue: lane j -> query (j&1), output channels [16*(j>>1), +16) ----
    const float rL0 = 1.0f / l0, rL1 = 1.0f / l1;
    float gg[32];
    const bool sel = (j & 1);
    #pragma unroll
    for (int c = 0; c < 32; ++c) gg[c] = sel ? acc1[c] * rL1 : acc0[c] * rL0;

    const int r = j >> 1;
    const float* xp = x + (size_t)b * (CHn * HWn) + nq;
    float* op = out + (size_t)b * (CHn * HWn) + nq;
    const float4* wpf4 = (const float4*)wpf;
    for (int oo = 0; oo < 16; ++oo) {
        const int o = (r << 4) | oo;
        float s = pbeta[o];
        #pragma unroll
        for (int c4 = 0; c4 < 8; ++c4) {
            float4 w = wpf4[o * 8 + c4];
            s += w.x * gg[4*c4] + w.y * gg[4*c4+1] + w.z * gg[4*c4+2] + w.w * gg[4*c4+3];
        }
        op[o * HWn] = xp[o * HWn] + s;
    }
}

// ------------------------------- launcher ------------------------------------
extern "C" void kernel_launch(void* const* d_in, const int* in_sizes, int n_in,
                              void* d_out, int out_size, void* d_ws, size_t ws_size,
                              hipStream_t stream)
{
    const float* x    = (const float*)d_in[0];
    const float* mem  = (const float*)d_in[1];
    const float* wq   = (const float*)d_in[2];
    const float* bq   = (const float*)d_in[3];
    const float* bnqs = (const float*)d_in[4];
    const float* bnqb = (const float*)d_in[5];
    const float* bnqm = (const float*)d_in[6];
    const float* bnqv = (const float*)d_in[7];
    const float* wk   = (const float*)d_in[8];
    const float* bk   = (const float*)d_in[9];
    const float* bnks = (const float*)d_in[10];
    const float* bnkb = (const float*)d_in[11];
    const float* bnkm = (const float*)d_in[12];
    const float* bnkv = (const float*)d_in[13];
    const float* wv   = (const float*)d_in[14];
    const float* bv   = (const float*)d_in[15];
    const float* bnvs = (const float*)d_in[16];
    const float* bnvb = (const float*)d_in[17];
    const float* bnvm = (const float*)d_in[18];
    const float* bnvv = (const float*)d_in[19];
    const float* wp   = (const float*)d_in[20];
    const float* bp   = (const float*)d_in[21];
    const float* bnps = (const float*)d_in[22];
    const float* bnpb = (const float*)d_in[23];
    const float* bnpm = (const float*)d_in[24];
    const float* bnpv = (const float*)d_in[25];
    const float* gam  = (const float*)d_in[26];

    (void)d_ws; (void)ws_size; (void)in_sizes; (void)n_in; (void)out_size;

    k_proj_kv<<<dim3(128), dim3(256), 0, stream>>>(mem,
        wk, bk, bnks, bnkb, bnkm, bnkv,
        wv, bv, bnvs, bnvb, bnvm, bnvv);
    k_attn2<<<dim3(512), dim3(256), 0, stream>>>(mem, x,
        wq, bq, bnqs, bnqb, bnqm, bnqv,
        wp, bp, bnps, bnpb, bnpm, bnpv, gam,
        (float*)d_out);
}